// Round 18
// baseline (42.250 us; speedup 1.0000x reference)
//
#include <hip/hip_runtime.h>

#define TWOPI 6.28318530717958647692f

#define BB 2
#define CC 32
#define NN 8192

typedef short bf16x8 __attribute__((ext_vector_type(8)));
typedef float f32x4  __attribute__((ext_vector_type(4)));
typedef float f32x2  __attribute__((ext_vector_type(2)));

__device__ __forceinline__ float2 cmul(float2 a, float2 b){
    return make_float2(fmaf(a.x, b.x, -(a.y*b.y)), fmaf(a.x, b.y, a.y*b.x));
}
__device__ __forceinline__ float2 conj2(float2 a){ return make_float2(a.x, -a.y); }
// 1-instr packed f32x2 -> bf16x2 (RNE), T12 recipe
__device__ __forceinline__ unsigned pk_bf16(float lo, float hi){
    unsigned r;
    asm("v_cvt_pk_bf16_f32 %0, %1, %2" : "=v"(r) : "v"(lo), "v"(hi));
    return r;
}
// HW sin/cos take REVOLUTIONS; valid since pos in [0,1)
__device__ __forceinline__ float hw_sin(float p){
    float r; asm("v_sin_f32 %0, %1" : "=v"(r) : "v"(p)); return r;
}
__device__ __forceinline__ float hw_cos(float p){
    float r; asm("v_cos_f32 %0, %1" : "=v"(r) : "v"(p)); return r;
}

// fragment-major offset of (row R, col C) within one (ks,b) partial slab:
__device__ __forceinline__ size_t fragoff(int R, int C){
    int cid = R/48, g3 = (R%48)/16, frow = R%16;
    int nt = C>>4, ll = (frow>>2)*16 + (C&15), r = frow&3;
    return ((size_t)cid*3 + g3)*512 + (size_t)nt*256 + (size_t)ll*4 + r;
}

// ---------------- standalone weight transpose (fallback path only) ----------------
__global__ __launch_bounds__(256)
void wtrans_kernel(const float* __restrict__ w1, const float* __restrict__ w2,
                   const float* __restrict__ w3, const float* __restrict__ w4,
                   float* __restrict__ wt){
    const int abz = blockIdx.x;
    const int q   = blockIdx.y;
    const float* w = (q==0)?w1:(q==1)?w2:(q==2)?w3:w4;
    const int tid = threadIdx.x;
    #pragma unroll
    for (int k=0;k<4;k++){
        int iop = tid + k*256;
        float2 v = *(const float2*)(w + ((size_t)iop*216 + abz)*2);
        *(float2*)(wt + (((size_t)q*216 + abz)*1024 + iop)*2) = v;
    }
}

// ============ fused: MFMA forward NUFFT (blocks 0..575) + COALESCED wtrans (576..831) ============
__global__ __launch_bounds__(256, 4)
void fused_fwd_kernel(const float* __restrict__ x, const float* __restrict__ pos,
                      const float* __restrict__ w1, const float* __restrict__ w2,
                      const float* __restrict__ w3, const float* __restrict__ w4,
                      float* __restrict__ wt, float* __restrict__ part){
    __shared__ __align__(16) char smem[32256];
    short (*P2)[16][72] = (short(*)[16][72])smem;        // 12*16*72*2 = 27,648 B
    short (*xl)[72]     = (short(*)[72])(smem + 27648);  // 32*72*2    =  4,608 B
    float2 (*T)[217]    = (float2(*)[217])smem;          // 16*217*8   = 27,776 B (wtrans view)

    const int bid = blockIdx.x;
    const int tid = threadIdx.x;

    if (bid >= 576){
        // ---- wtrans role: tile transpose, coalesced reads ----
        const int wid = bid - 576;          // 0..255
        const int q   = wid >> 6;           // 0..3
        const int it  = wid & 63;           // 0..63
        const int iop0 = it*16;
        const float* w = (q==0)?w1:(q==1)?w2:(q==2)?w3:w4;
        #pragma unroll
        for (int r=0;r<16;r++){
            if (tid < 216)
                T[r][tid] = *(const float2*)(w + ((size_t)(iop0+r)*216 + tid)*2);
        }
        __syncthreads();
        #pragma unroll
        for (int k2=0;k2<14;k2++){
            int idx = k2*256 + tid;         // 0..3583 ; 3456 valid
            int abz = idx >> 4;
            int r   = idx & 15;
            if (abz < 216)
                *(float2*)(wt + (((size_t)q*216 + abz)*1024 + iop0 + r)*2) = T[r][abz];
        }
        return;
    }

    // ---- fwd role ----
    const int ks  = bid & 31;            // 0..31
    const int bm  = (bid >> 5) % 9;      // 0..8
    const int b   = bid / 288;           // 0..1
    const int l   = tid & 63;
    const int w   = tid >> 6;            // wave 0..3
    const int cid = 4*bm + w;            // chunk 0..35 (wave-uniform)
    const int c4k = cid / 9;
    const int lc  = cid % 9;
    const int kxb = (c4k==0) ? 0 : (c4k==1) ? 3 : (c4k==2) ? -6 : -3;
    const int kx0 = kxb + lc/3;
    const int lm3 = lc % 3;

    f32x4 acc[3][2];
    #pragma unroll
    for (int i=0;i<3;i++)
      #pragma unroll
      for (int j=0;j<2;j++) acc[i][j] = (f32x4){0.f,0.f,0.f,0.f};

    #pragma unroll 1
    for (int rnd=0; rnd<4; ++rnd){
        const int n0 = ks*256 + rnd*64;
        __syncthreads();
        // stage x tile (fp32 -> bf16, packed): 32 c x 64 n
        #pragma unroll
        for (int k=0;k<2;k++){
            int idx = k*256 + tid;       // float4 index 0..511
            int c = idx >> 4;
            int j = idx & 15;
            float4 v = *(const float4*)(x + ((size_t)b*CC + c)*NN + n0 + j*4);
            unsigned p0 = pk_bf16(v.x, v.y);
            unsigned p1 = pk_bf16(v.z, v.w);
            *(uint2*)(&xl[c][j*4]) = make_uint2(p0, p1);
        }
        // phase-gen: wave w stages chunk cid for point l (ky-ladder, per-lane hw trig)
        {
            const int n = n0 + l;
            const float px = pos[((size_t)b*NN + n)*3 + 0];
            const float py = pos[((size_t)b*NN + n)*3 + 1];
            const float pz = pos[((size_t)b*NN + n)*3 + 2];
            const float2 Exf = make_float2(hw_cos(px), -hw_sin(px));   // exp(-i*2pi*px)
            const float2 Eyf = make_float2(hw_cos(py), -hw_sin(py));
            const float2 Ezf = make_float2(hw_cos(pz), -hw_sin(pz));
            float2 e = make_float2(1.f, 0.f);
            const int ax = kx0 < 0 ? -kx0 : kx0;
            #pragma unroll
            for (int i2=0;i2<6;i2++) if (i2 < ax) e = cmul(e, Exf);
            if (kx0 < 0) e = conj2(e);
            const float2 y2  = cmul(Eyf, Eyf);
            const float2 y4  = cmul(y2, y2);
            if      (lm3 == 1) e = cmul(e, y4);
            else if (lm3 == 2) e = cmul(e, conj2(y4));
            const float2 y8  = cmul(y4, y4);
            const float2 y11 = cmul(cmul(y8, y2), Eyf);
            float2 Sv[4];
            Sv[0] = e;
            Sv[1] = cmul(Sv[0], Eyf);
            Sv[2] = cmul(Sv[1], (lm3==1) ? conj2(y11) : Eyf);
            Sv[3] = cmul(Sv[2], Eyf);
            #pragma unroll
            for (int s2=0; s2<4; ++s2){
                float2 ee = Sv[s2];
                #pragma unroll
                for (int kz=0; kz<6; ++kz){
                    const int g  = 6*s2 + kz;      // 0..23
                    const int g3 = g >> 3;
                    const int j  = g & 7;
                    unsigned pv = pk_bf16(ee.x, ee.y);
                    P2[w*3+g3][2*j  ][l] = (short)(pv & 0xffffu);
                    P2[w*3+g3][2*j+1][l] = (short)(pv >> 16);
                    if (kz < 5) ee = cmul(ee, Ezf);
                }
            }
        }
        __syncthreads();
        // MFMA: 2 ksteps x 3 groups x 2 channel-halves
        #pragma unroll
        for (int kstep=0; kstep<2; ++kstep){
            const int kn = kstep*32 + (l>>4)*8;
            bf16x8 bfr0 = *(const bf16x8*)(&xl[(l&15)     ][kn]);
            bf16x8 bfr1 = *(const bf16x8*)(&xl[(l&15) + 16][kn]);
            #pragma unroll
            for (int g3=0; g3<3; ++g3){
                bf16x8 afr = *(const bf16x8*)(&P2[w*3+g3][l&15][kn]);
                acc[g3][0] = __builtin_amdgcn_mfma_f32_16x16x32_bf16(afr, bfr0, acc[g3][0],0,0,0);
                acc[g3][1] = __builtin_amdgcn_mfma_f32_16x16x32_bf16(afr, bfr1, acc[g3][1],0,0,0);
            }
        }
    }
    // store partials fragment-major, NON-TEMPORAL (write-once)
    float* pb = part + ((((size_t)ks*BB + b)*36 + cid)*3)*512;
    #pragma unroll
    for (int g3=0; g3<3; ++g3)
      #pragma unroll
      for (int nt=0; nt<2; ++nt)
        __builtin_nontemporal_store(acc[g3][nt],
            (f32x4*)(pb + (size_t)(g3*2+nt)*256 + (size_t)l*4));
}

// ---------------- atomic fallback forward (fragment-major into part[0]) ----------------
__global__ __launch_bounds__(128, 2)
void fwd_atomic_kernel(const float* __restrict__ x, const float* __restrict__ pos,
                       float* __restrict__ F){
    const int tid = threadIdx.x;
    const int colslot = tid & 15;
    const int cs = tid >> 4;
    const int col = blockIdx.y * 16 + colslot;  // ix*12 + iy
    const int ixm = col / 12;
    const int iym = col % 12;
    const int b   = blockIdx.z;
    const int nb0 = blockIdx.x * 128;

    __shared__ float2 exl[12][65];
    __shared__ float2 eyl[12][65];
    __shared__ float2 ezt[64][8];
    __shared__ float  xl[CC][68];

    float acc[6][4][2];
    #pragma unroll
    for (int z=0;z<6;z++)
      #pragma unroll
      for (int j=0;j<4;j++){ acc[z][j][0]=0.f; acc[z][j][1]=0.f; }

    for (int t=0; t<2; ++t){
        const int nb = nb0 + t*64;
        __syncthreads();
        if (tid < 64){
            const int n = nb + tid;
            const float px = pos[((size_t)b*NN + n)*3 + 0];
            const float py = pos[((size_t)b*NN + n)*3 + 1];
            const float pz = pos[((size_t)b*NN + n)*3 + 2];
            float s, c;
            float2 pw[7];
            s = hw_sin(px); c = hw_cos(px);
            { float2 e1 = make_float2(c, -s);
              pw[0] = make_float2(1.f, 0.f);
              #pragma unroll
              for (int k=1;k<7;k++) pw[k] = cmul(pw[k-1], e1);
              #pragma unroll
              for (int k=0;k<6;k++) exl[k][tid] = pw[k];
              #pragma unroll
              for (int k=6;k<12;k++) exl[k][tid] = make_float2(pw[12-k].x, -pw[12-k].y);
            }
            s = hw_sin(py); c = hw_cos(py);
            { float2 e1 = make_float2(c, -s);
              pw[0] = make_float2(1.f, 0.f);
              #pragma unroll
              for (int k=1;k<7;k++) pw[k] = cmul(pw[k-1], e1);
              #pragma unroll
              for (int k=0;k<6;k++) eyl[k][tid] = pw[k];
              #pragma unroll
              for (int k=6;k<12;k++) eyl[k][tid] = make_float2(pw[12-k].x, -pw[12-k].y);
            }
            s = hw_sin(pz); c = hw_cos(pz);
            { float2 e1 = make_float2(c, -s);
              float2 qv = make_float2(1.f, 0.f);
              #pragma unroll
              for (int k=0;k<6;k++){ ezt[tid][k] = qv; qv = cmul(qv, e1); }
            }
        }
        #pragma unroll
        for (int k=0;k<4;k++){
            int v = tid + k*128;
            int c = v >> 4;
            int j = v & 15;
            float4 xv = *(const float4*)(x + (size_t)(b*CC + c)*NN + nb + j*4);
            *(float4*)(&xl[c][j*4]) = xv;
        }
        __syncthreads();

        #pragma unroll 2
        for (int np=0; np<64; ++np){
            float2 rex = exl[ixm][np];
            float2 rey = eyl[iym][np];
            float2 exy = cmul(rex, rey);
            float xv0 = xl[cs*4+0][np];
            float xv1 = xl[cs*4+1][np];
            float xv2 = xl[cs*4+2][np];
            float xv3 = xl[cs*4+3][np];
            const float4* ezp = (const float4*)(&ezt[np][0]);
            float4 ea = ezp[0], eb2 = ezp[1], ec = ezp[2];
            float2 ezv[6];
            ezv[0] = make_float2(ea.x, ea.y);  ezv[1] = make_float2(ea.z, ea.w);
            ezv[2] = make_float2(eb2.x, eb2.y); ezv[3] = make_float2(eb2.z, eb2.w);
            ezv[4] = make_float2(ec.x, ec.y);  ezv[5] = make_float2(ec.z, ec.w);
            #pragma unroll
            for (int z=0; z<6; ++z){
                float2 ph = cmul(exy, ezv[z]);
                acc[z][0][0] = fmaf(ph.x, xv0, acc[z][0][0]);
                acc[z][0][1] = fmaf(ph.y, xv0, acc[z][0][1]);
                acc[z][1][0] = fmaf(ph.x, xv1, acc[z][1][0]);
                acc[z][1][1] = fmaf(ph.y, xv1, acc[z][1][1]);
                acc[z][2][0] = fmaf(ph.x, xv2, acc[z][2][0]);
                acc[z][2][1] = fmaf(ph.y, xv2, acc[z][2][1]);
                acc[z][3][0] = fmaf(ph.x, xv3, acc[z][3][0]);
                acc[z][3][1] = fmaf(ph.y, xv3, acc[z][3][1]);
            }
        }
    }

    const int c0 = cs*4;
    const int c4f = ixm/3;
    const int tb  = (ixm%3)*72 + iym*6;
    float* Fb = F + (size_t)b*55296;
    #pragma unroll
    for (int z=0;z<6;z++)
      #pragma unroll
      for (int j=0;j<4;j++){
        const int R = c4f*432 + 2*(tb + z);
        atomicAdd(Fb + fragoff(R,   c0 + j), acc[z][j][0]);
        atomicAdd(Fb + fragoff(R+1, c0 + j), acc[z][j][1]);
      }
}

// ---------------- fused split-K reduce + spectral mix + channel fold -> bf16 A ----------------
template<int NK>
__global__ __launch_bounds__(128)
void mix_kernel(const float* __restrict__ part, const float* __restrict__ wt,
                short* __restrict__ Abf){
    const int tid = threadIdx.x;
    const int o  = tid & 31;
    const int ml = tid >> 5;      // 0..3
    const int b  = blockIdx.y;
    const int m0 = blockIdx.x * 4;

    __shared__ float xs[256];
    __shared__ float os[4][32][2];

    // fragment-gather split-K reduce of the 8-row x 32-col tile
    {
        const int mm0 = m0 % 216, c4m = m0 / 216;
        const int q0  = 2*mm0;                 // multiple of 8
        const int cid = c4m*9 + q0/48;
        const int g3  = (q0 % 48) / 16;
        const int lh  = (q0 % 16) >> 3;        // 0 or 1: lane-half
        const int v   = 2*tid;
        const int nt  = v >> 7;
        const int rem = v & 127;
        const int lp  = rem >> 2;              // 0..31
        const int rr  = rem & 3;               // 0 or 2
        const float* pb = part + (((size_t)b*36 + cid)*3 + g3)*512
                        + (size_t)nt*256 + (size_t)(lh*32 + lp)*4 + rr;
        float s0 = 0.f, s1 = 0.f;
        #pragma unroll 8
        for (int k=0;k<NK;k++){
            f32x2 vv = __builtin_nontemporal_load((const f32x2*)(pb + (size_t)k*110592));
            s0 += vv[0]; s1 += vv[1];
        }
        const int jA = ((lp>>4)<<2) + rr;      // row-in-tile of s0; s1 at jA+1
        const int ci = nt*16 + (lp & 15);
        xs[jA*32 + ci]       = s0;
        xs[(jA+1)*32 + ci]   = s1;
    }
    __syncthreads();

    const int m  = m0 + ml;
    const int ix = m / 72;
    const int iy = (m / 6) % 12;
    const int iz = m % 6;
    const int q  = (ix>=6 ? 1 : 0) + (iy>=6 ? 2 : 0);
    const int a  = ix % 6;
    const int bb2 = iy % 6;
    const int abz = (a*6 + bb2)*6 + iz;
    const float* wq = wt + ((size_t)q*216 + abz)*2048;

    float orr = 0.f, oii = 0.f;
    #pragma unroll 8
    for (int i=0;i<32;i++){
        float xr = xs[ml*64 + i];
        float xi = xs[ml*64 + 32 + i];
        float2 wv = *(const float2*)(wq + (i*32 + o)*2);
        orr = fmaf(xr, wv.x, orr); orr = fmaf(-xi, wv.y, orr);
        oii = fmaf(xr, wv.y, oii); oii = fmaf( xi, wv.x, oii);
    }
    os[ml][o][0] = orr;
    os[ml][o][1] = oii;
    __syncthreads();
    if (o < 16){
        const float sc2 = 2.0f / (float)NN;
        float tr =  (os[ml][o][0] + os[ml][31-o][0]) * sc2;
        float ti = -((os[ml][o][1] + os[ml][31-o][1]) * sc2);
        const int mc4 = m / 216;
        const int mr  = m % 216;
        const int kk  = mr >> 2;
        const int qq  = mr & 3;
        unsigned pv = pk_bf16(tr, ti);
        *(unsigned*)(Abf + (size_t)b*27648 + ((size_t)kk*64 + mc4*16 + o)*8 + 2*qq) = pv;
    }
}

// ---------------- inverse NUFFT: MFMA, 12-wave blocks, coalesced A-loads ----------------
__global__ __launch_bounds__(768)
void inv_kernel(const float* __restrict__ pos, const short* __restrict__ Abf,
                float* __restrict__ y){
    const int tid = threadIdx.x;
    const int og  = tid >> 8;            // 0..2  (o-group)
    const int w4  = (tid >> 6) & 3;      // n-tile within block
    const int l   = tid & 63;
    const int col = l & 15;
    const int c4  = l >> 4;
    const int b   = blockIdx.y;
    const int n   = blockIdx.x*64 + w4*16 + col;

    __shared__ float red[2][4][16][17];

    const float px = pos[((size_t)b*NN + n)*3 + 0];
    const float py = pos[((size_t)b*NN + n)*3 + 1];
    const float pz = pos[((size_t)b*NN + n)*3 + 2];
    const float2 Ex = make_float2(hw_cos(px), hw_sin(px));   // exp(+i*2pi*px)
    const float2 Ey = make_float2(hw_cos(py), hw_sin(py));
    const float2 Ez = make_float2(hw_cos(pz), hw_sin(pz));

    const float2 yy2 = cmul(Ey, Ey);
    const float2 yy4 = cmul(yy2, yy2);
    const float2 yy8 = cmul(yy4, yy4);
    const float2 cj11 = conj2(cmul(cmul(yy8, yy2), Ey));   // Ey^-11
    const float2 x3  = cmul(cmul(Ex, Ex), Ex);
    const float2 x6  = cmul(x3, x3);
    float2 e = (c4==0) ? make_float2(1.f, 0.f)
             : (c4==1) ? x3
             : (c4==2) ? conj2(x6)
             :           conj2(x3);
    if (og >= 1) e = cmul(e, Ex);        // o-group start: kx += og
    if (og == 2) e = cmul(e, Ex);

    // coalesced fragment-major A: lane l reads 16B at base + l*16B, step 1KB per u2
    const short* Ab = Abf + (size_t)b*27648 + (size_t)og*18*512 + (size_t)l*8;
    f32x4 acc = {0.f, 0.f, 0.f, 0.f};

    union BU { unsigned u[4]; bf16x8 v; };

    // ky-ladder: segment advance S *= Ey (or Ey^-11 at the 5->-6 wrap), 5-deep Ez chains
    float2 S  = e;
    float2 ee = S;
    #pragma unroll
    for (int u2=0; u2<18; ++u2){
        BU bu;
        #pragma unroll
        for (int qq=0; qq<4; ++qq){
            const int g = 4*u2 + qq;              // 0..71 within o-group
            if (g > 0){
                if (g % 6) ee = cmul(ee, Ez);
                else { S = cmul(S, (g==36) ? cj11 : Ey); ee = S; }
            }
            bu.u[qq] = pk_bf16(ee.x, ee.y);
        }
        bf16x8 afr = *(const bf16x8*)(Ab + (size_t)u2*512);
        acc = __builtin_amdgcn_mfma_f32_16x16x32_bf16(afr, bu.v, acc, 0, 0, 0);
    }

    if (og >= 1){
        #pragma unroll
        for (int r=0; r<4; ++r) red[og-1][w4][c4*4 + r][col] = acc[r];
    }
    __syncthreads();
    if (og == 0){
        float* yb = y + (size_t)b*CC*NN + n;
        #pragma unroll
        for (int r=0; r<4; ++r){
            const int ch = c4*4 + r;
            float v = acc[r] + red[0][w4][ch][col] + red[1][w4][ch][col];
            __builtin_nontemporal_store(v, yb + (size_t)ch*NN);
            __builtin_nontemporal_store(v, yb + (size_t)(31-ch)*NN);
        }
    }
}

extern "C" void kernel_launch(void* const* d_in, const int* in_sizes, int n_in,
                              void* d_out, int out_size, void* d_ws, size_t ws_size,
                              hipStream_t stream){
    const float* x   = (const float*)d_in[0];
    const float* pos = (const float*)d_in[1];
    const float* w1  = (const float*)d_in[2];
    const float* w2  = (const float*)d_in[3];
    const float* w3  = (const float*)d_in[4];
    const float* w4  = (const float*)d_in[5];
    float* out = (float*)d_out;
    char* wsb = (char*)d_ws;

    // ws layout (bytes):
    float* wt    = (float*)(wsb);                // 4*216*1024*2*4 = 7,077,888
    short* Abf   = (short*)(wsb + 7520256);      // 2*27648*2     =   110,592
    float* part2 = (float*)(wsb + 7741440);      // 32*110592*4   = 14,155,776
    const bool use_part = (ws_size >= 21897216ull);

    // DIAGNOSTIC: fused_fwd launched TWICE (idempotent — rewrites identical
    // wt/part values from unmodified inputs). fwd = T - 30.9 us exactly.
    if (use_part){
        fused_fwd_kernel<<<dim3(832), 256, 0, stream>>>(x, pos, w1, w2, w3, w4, wt, part2);
        fused_fwd_kernel<<<dim3(832), 256, 0, stream>>>(x, pos, w1, w2, w3, w4, wt, part2);
        mix_kernel<32><<<dim3(216,2), 128, 0, stream>>>(part2, wt, Abf);
    } else {
        wtrans_kernel<<<dim3(216,4), 256, 0, stream>>>(w1, w2, w3, w4, wt);
        (void)hipMemsetAsync(part2, 0, 442368, stream);
        fwd_atomic_kernel<<<dim3(64,9,2), 128, 0, stream>>>(x, pos, part2);
        mix_kernel<1><<<dim3(216,2), 128, 0, stream>>>(part2, wt, Abf);
    }

    inv_kernel<<<dim3(NN/64, BB), 768, 0, stream>>>(pos, Abf, out);
}

// Round 20
// 30.759 us; speedup vs baseline: 1.3736x; 1.3736x over previous
//
#include <hip/hip_runtime.h>

#define TWOPI 6.28318530717958647692f

#define BB 2
#define CC 32
#define NN 8192

typedef short bf16x8 __attribute__((ext_vector_type(8)));
typedef float f32x4  __attribute__((ext_vector_type(4)));
typedef float f32x2  __attribute__((ext_vector_type(2)));

__device__ __forceinline__ float2 cmul(float2 a, float2 b){
    return make_float2(fmaf(a.x, b.x, -(a.y*b.y)), fmaf(a.x, b.y, a.y*b.x));
}
__device__ __forceinline__ float2 conj2(float2 a){ return make_float2(a.x, -a.y); }
// 1-instr packed f32x2 -> bf16x2 (RNE), T12 recipe
__device__ __forceinline__ unsigned pk_bf16(float lo, float hi){
    unsigned r;
    asm("v_cvt_pk_bf16_f32 %0, %1, %2" : "=v"(r) : "v"(lo), "v"(hi));
    return r;
}
// HW sin/cos take REVOLUTIONS; valid since pos in [0,1)
__device__ __forceinline__ float hw_sin(float p){
    float r; asm("v_sin_f32 %0, %1" : "=v"(r) : "v"(p)); return r;
}
__device__ __forceinline__ float hw_cos(float p){
    float r; asm("v_cos_f32 %0, %1" : "=v"(r) : "v"(p)); return r;
}

// fragment-major offset of (row R, col C) within one (ks,b) partial slab:
__device__ __forceinline__ size_t fragoff(int R, int C){
    int cid = R/48, g3 = (R%48)/16, frow = R%16;
    int nt = C>>4, ll = (frow>>2)*16 + (C&15), r = frow&3;
    return ((size_t)cid*3 + g3)*512 + (size_t)nt*256 + (size_t)ll*4 + r;
}

// ---------------- standalone weight transpose (fallback path only) ----------------
__global__ __launch_bounds__(256)
void wtrans_kernel(const float* __restrict__ w1, const float* __restrict__ w2,
                   const float* __restrict__ w3, const float* __restrict__ w4,
                   float* __restrict__ wt){
    const int abz = blockIdx.x;
    const int q   = blockIdx.y;
    const float* w = (q==0)?w1:(q==1)?w2:(q==2)?w3:w4;
    const int tid = threadIdx.x;
    #pragma unroll
    for (int k=0;k<4;k++){
        int iop = tid + k*256;
        float2 v = *(const float2*)(w + ((size_t)iop*216 + abz)*2);
        *(float2*)(wt + (((size_t)q*216 + abz)*1024 + iop)*2) = v;
    }
}

// ============ fused: MFMA forward NUFFT (blocks 0..575) + COALESCED wtrans (576..831) ============
__global__ __launch_bounds__(256, 4)
void fused_fwd_kernel(const float* __restrict__ x, const float* __restrict__ pos,
                      const float* __restrict__ w1, const float* __restrict__ w2,
                      const float* __restrict__ w3, const float* __restrict__ w4,
                      float* __restrict__ wt, float* __restrict__ part){
    __shared__ __align__(16) char smem[32256];
    short (*P2)[16][72] = (short(*)[16][72])smem;        // 12*16*72*2 = 27,648 B
    short (*xl)[72]     = (short(*)[72])(smem + 27648);  // 32*72*2    =  4,608 B
    float2 (*T)[217]    = (float2(*)[217])smem;          // 16*217*8   = 27,776 B (wtrans view)

    const int bid = blockIdx.x;
    const int tid = threadIdx.x;

    if (bid >= 576){
        // ---- wtrans role: tile transpose, coalesced reads ----
        const int wid = bid - 576;          // 0..255
        const int q   = wid >> 6;           // 0..3
        const int it  = wid & 63;           // 0..63
        const int iop0 = it*16;
        const float* w = (q==0)?w1:(q==1)?w2:(q==2)?w3:w4;
        #pragma unroll
        for (int r=0;r<16;r++){
            if (tid < 216)
                T[r][tid] = *(const float2*)(w + ((size_t)(iop0+r)*216 + tid)*2);
        }
        __syncthreads();
        #pragma unroll
        for (int k2=0;k2<14;k2++){
            int idx = k2*256 + tid;         // 0..3583 ; 3456 valid
            int abz = idx >> 4;
            int r   = idx & 15;
            if (abz < 216)
                *(float2*)(wt + (((size_t)q*216 + abz)*1024 + iop0 + r)*2) = T[r][abz];
        }
        return;
    }

    // ---- fwd role ----
    const int ks  = bid & 31;            // 0..31
    const int bm  = (bid >> 5) % 9;      // 0..8
    const int b   = bid / 288;           // 0..1
    const int l   = tid & 63;
    const int w   = tid >> 6;            // wave 0..3
    const int cid = 4*bm + w;            // chunk 0..35 (wave-uniform)
    const int c4k = cid / 9;
    const int lc  = cid % 9;
    const int kxb = (c4k==0) ? 0 : (c4k==1) ? 3 : (c4k==2) ? -6 : -3;
    const int kx0 = kxb + lc/3;
    const int lm3 = lc % 3;

    f32x4 acc[3][2];
    #pragma unroll
    for (int i=0;i<3;i++)
      #pragma unroll
      for (int j=0;j<2;j++) acc[i][j] = (f32x4){0.f,0.f,0.f,0.f};

    #pragma unroll 1
    for (int rnd=0; rnd<4; ++rnd){
        const int n0 = ks*256 + rnd*64;
        __syncthreads();
        // stage x tile (fp32 -> bf16, packed): 32 c x 64 n
        #pragma unroll
        for (int k=0;k<2;k++){
            int idx = k*256 + tid;       // float4 index 0..511
            int c = idx >> 4;
            int j = idx & 15;
            float4 v = *(const float4*)(x + ((size_t)b*CC + c)*NN + n0 + j*4);
            unsigned p0 = pk_bf16(v.x, v.y);
            unsigned p1 = pk_bf16(v.z, v.w);
            *(uint2*)(&xl[c][j*4]) = make_uint2(p0, p1);
        }
        // phase-gen: wave w stages chunk cid for point l (ky-ladder, per-lane hw trig)
        {
            const int n = n0 + l;
            const float px = pos[((size_t)b*NN + n)*3 + 0];
            const float py = pos[((size_t)b*NN + n)*3 + 1];
            const float pz = pos[((size_t)b*NN + n)*3 + 2];
            const float2 Exf = make_float2(hw_cos(px), -hw_sin(px));   // exp(-i*2pi*px)
            const float2 Eyf = make_float2(hw_cos(py), -hw_sin(py));
            const float2 Ezf = make_float2(hw_cos(pz), -hw_sin(pz));
            float2 e = make_float2(1.f, 0.f);
            const int ax = kx0 < 0 ? -kx0 : kx0;
            #pragma unroll
            for (int i2=0;i2<6;i2++) if (i2 < ax) e = cmul(e, Exf);
            if (kx0 < 0) e = conj2(e);
            const float2 y2  = cmul(Eyf, Eyf);
            const float2 y4  = cmul(y2, y2);
            if      (lm3 == 1) e = cmul(e, y4);
            else if (lm3 == 2) e = cmul(e, conj2(y4));
            const float2 y8  = cmul(y4, y4);
            const float2 y11 = cmul(cmul(y8, y2), Eyf);
            float2 Sv[4];
            Sv[0] = e;
            Sv[1] = cmul(Sv[0], Eyf);
            Sv[2] = cmul(Sv[1], (lm3==1) ? conj2(y11) : Eyf);
            Sv[3] = cmul(Sv[2], Eyf);
            #pragma unroll
            for (int s2=0; s2<4; ++s2){
                float2 ee = Sv[s2];
                #pragma unroll
                for (int kz=0; kz<6; ++kz){
                    const int g  = 6*s2 + kz;      // 0..23
                    const int g3 = g >> 3;
                    const int j  = g & 7;
                    unsigned pv = pk_bf16(ee.x, ee.y);
                    P2[w*3+g3][2*j  ][l] = (short)(pv & 0xffffu);
                    P2[w*3+g3][2*j+1][l] = (short)(pv >> 16);
                    if (kz < 5) ee = cmul(ee, Ezf);
                }
            }
        }
        __syncthreads();
        // MFMA: 2 ksteps x 3 groups x 2 channel-halves
        #pragma unroll
        for (int kstep=0; kstep<2; ++kstep){
            const int kn = kstep*32 + (l>>4)*8;
            bf16x8 bfr0 = *(const bf16x8*)(&xl[(l&15)     ][kn]);
            bf16x8 bfr1 = *(const bf16x8*)(&xl[(l&15) + 16][kn]);
            #pragma unroll
            for (int g3=0; g3<3; ++g3){
                bf16x8 afr = *(const bf16x8*)(&P2[w*3+g3][l&15][kn]);
                acc[g3][0] = __builtin_amdgcn_mfma_f32_16x16x32_bf16(afr, bfr0, acc[g3][0],0,0,0);
                acc[g3][1] = __builtin_amdgcn_mfma_f32_16x16x32_bf16(afr, bfr1, acc[g3][1],0,0,0);
            }
        }
    }
    // store partials fragment-major, NON-TEMPORAL (write-once)
    float* pb = part + ((((size_t)ks*BB + b)*36 + cid)*3)*512;
    #pragma unroll
    for (int g3=0; g3<3; ++g3)
      #pragma unroll
      for (int nt=0; nt<2; ++nt)
        __builtin_nontemporal_store(acc[g3][nt],
            (f32x4*)(pb + (size_t)(g3*2+nt)*256 + (size_t)l*4));
}

// ---------------- atomic fallback forward (fragment-major into part[0]) ----------------
__global__ __launch_bounds__(128, 2)
void fwd_atomic_kernel(const float* __restrict__ x, const float* __restrict__ pos,
                       float* __restrict__ F){
    const int tid = threadIdx.x;
    const int colslot = tid & 15;
    const int cs = tid >> 4;
    const int col = blockIdx.y * 16 + colslot;  // ix*12 + iy
    const int ixm = col / 12;
    const int iym = col % 12;
    const int b   = blockIdx.z;
    const int nb0 = blockIdx.x * 128;

    __shared__ float2 exl[12][65];
    __shared__ float2 eyl[12][65];
    __shared__ float2 ezt[64][8];
    __shared__ float  xl[CC][68];

    float acc[6][4][2];
    #pragma unroll
    for (int z=0;z<6;z++)
      #pragma unroll
      for (int j=0;j<4;j++){ acc[z][j][0]=0.f; acc[z][j][1]=0.f; }

    for (int t=0; t<2; ++t){
        const int nb = nb0 + t*64;
        __syncthreads();
        if (tid < 64){
            const int n = nb + tid;
            const float px = pos[((size_t)b*NN + n)*3 + 0];
            const float py = pos[((size_t)b*NN + n)*3 + 1];
            const float pz = pos[((size_t)b*NN + n)*3 + 2];
            float s, c;
            float2 pw[7];
            s = hw_sin(px); c = hw_cos(px);
            { float2 e1 = make_float2(c, -s);
              pw[0] = make_float2(1.f, 0.f);
              #pragma unroll
              for (int k=1;k<7;k++) pw[k] = cmul(pw[k-1], e1);
              #pragma unroll
              for (int k=0;k<6;k++) exl[k][tid] = pw[k];
              #pragma unroll
              for (int k=6;k<12;k++) exl[k][tid] = make_float2(pw[12-k].x, -pw[12-k].y);
            }
            s = hw_sin(py); c = hw_cos(py);
            { float2 e1 = make_float2(c, -s);
              pw[0] = make_float2(1.f, 0.f);
              #pragma unroll
              for (int k=1;k<7;k++) pw[k] = cmul(pw[k-1], e1);
              #pragma unroll
              for (int k=0;k<6;k++) eyl[k][tid] = pw[k];
              #pragma unroll
              for (int k=6;k<12;k++) eyl[k][tid] = make_float2(pw[12-k].x, -pw[12-k].y);
            }
            s = hw_sin(pz); c = hw_cos(pz);
            { float2 e1 = make_float2(c, -s);
              float2 qv = make_float2(1.f, 0.f);
              #pragma unroll
              for (int k=0;k<6;k++){ ezt[tid][k] = qv; qv = cmul(qv, e1); }
            }
        }
        #pragma unroll
        for (int k=0;k<4;k++){
            int v = tid + k*128;
            int c = v >> 4;
            int j = v & 15;
            float4 xv = *(const float4*)(x + (size_t)(b*CC + c)*NN + nb + j*4);
            *(float4*)(&xl[c][j*4]) = xv;
        }
        __syncthreads();

        #pragma unroll 2
        for (int np=0; np<64; ++np){
            float2 rex = exl[ixm][np];
            float2 rey = eyl[iym][np];
            float2 exy = cmul(rex, rey);
            float xv0 = xl[cs*4+0][np];
            float xv1 = xl[cs*4+1][np];
            float xv2 = xl[cs*4+2][np];
            float xv3 = xl[cs*4+3][np];
            const float4* ezp = (const float4*)(&ezt[np][0]);
            float4 ea = ezp[0], eb2 = ezp[1], ec = ezp[2];
            float2 ezv[6];
            ezv[0] = make_float2(ea.x, ea.y);  ezv[1] = make_float2(ea.z, ea.w);
            ezv[2] = make_float2(eb2.x, eb2.y); ezv[3] = make_float2(eb2.z, eb2.w);
            ezv[4] = make_float2(ec.x, ec.y);  ezv[5] = make_float2(ec.z, ec.w);
            #pragma unroll
            for (int z=0; z<6; ++z){
                float2 ph = cmul(exy, ezv[z]);
                acc[z][0][0] = fmaf(ph.x, xv0, acc[z][0][0]);
                acc[z][0][1] = fmaf(ph.y, xv0, acc[z][0][1]);
                acc[z][1][0] = fmaf(ph.x, xv1, acc[z][1][0]);
                acc[z][1][1] = fmaf(ph.y, xv1, acc[z][1][1]);
                acc[z][2][0] = fmaf(ph.x, xv2, acc[z][2][0]);
                acc[z][2][1] = fmaf(ph.y, xv2, acc[z][2][1]);
                acc[z][3][0] = fmaf(ph.x, xv3, acc[z][3][0]);
                acc[z][3][1] = fmaf(ph.y, xv3, acc[z][3][1]);
            }
        }
    }

    const int c0 = cs*4;
    const int c4f = ixm/3;
    const int tb  = (ixm%3)*72 + iym*6;
    float* Fb = F + (size_t)b*55296;
    #pragma unroll
    for (int z=0;z<6;z++)
      #pragma unroll
      for (int j=0;j<4;j++){
        const int R = c4f*432 + 2*(tb + z);
        atomicAdd(Fb + fragoff(R,   c0 + j), acc[z][j][0]);
        atomicAdd(Fb + fragoff(R+1, c0 + j), acc[z][j][1]);
      }
}

// ---------------- fused split-K reduce + spectral mix + channel fold -> bf16 A ----------------
template<int NK>
__global__ __launch_bounds__(128)
void mix_kernel(const float* __restrict__ part, const float* __restrict__ wt,
                short* __restrict__ Abf){
    const int tid = threadIdx.x;
    const int o  = tid & 31;
    const int ml = tid >> 5;      // 0..3
    const int b  = blockIdx.y;
    const int m0 = blockIdx.x * 4;

    __shared__ float xs[256];
    __shared__ float os[4][32][2];

    // fragment-gather split-K reduce of the 8-row x 32-col tile
    {
        const int mm0 = m0 % 216, c4m = m0 / 216;
        const int q0  = 2*mm0;                 // multiple of 8
        const int cid = c4m*9 + q0/48;
        const int g3  = (q0 % 48) / 16;
        const int lh  = (q0 % 16) >> 3;        // 0 or 1: lane-half
        const int v   = 2*tid;
        const int nt  = v >> 7;
        const int rem = v & 127;
        const int lp  = rem >> 2;              // 0..31
        const int rr  = rem & 3;               // 0 or 2
        const float* pb = part + (((size_t)b*36 + cid)*3 + g3)*512
                        + (size_t)nt*256 + (size_t)(lh*32 + lp)*4 + rr;
        float s0 = 0.f, s1 = 0.f;
        #pragma unroll 8
        for (int k=0;k<NK;k++){
            f32x2 vv = __builtin_nontemporal_load((const f32x2*)(pb + (size_t)k*110592));
            s0 += vv[0]; s1 += vv[1];
        }
        const int jA = ((lp>>4)<<2) + rr;      // row-in-tile of s0; s1 at jA+1
        const int ci = nt*16 + (lp & 15);
        xs[jA*32 + ci]       = s0;
        xs[(jA+1)*32 + ci]   = s1;
    }
    __syncthreads();

    const int m  = m0 + ml;
    const int ix = m / 72;
    const int iy = (m / 6) % 12;
    const int iz = m % 6;
    const int q  = (ix>=6 ? 1 : 0) + (iy>=6 ? 2 : 0);
    const int a  = ix % 6;
    const int bb2 = iy % 6;
    const int abz = (a*6 + bb2)*6 + iz;
    const float* wq = wt + ((size_t)q*216 + abz)*2048;

    float orr = 0.f, oii = 0.f;
    #pragma unroll 8
    for (int i=0;i<32;i++){
        float xr = xs[ml*64 + i];
        float xi = xs[ml*64 + 32 + i];
        float2 wv = *(const float2*)(wq + (i*32 + o)*2);
        orr = fmaf(xr, wv.x, orr); orr = fmaf(-xi, wv.y, orr);
        oii = fmaf(xr, wv.y, oii); oii = fmaf( xi, wv.x, oii);
    }
    os[ml][o][0] = orr;
    os[ml][o][1] = oii;
    __syncthreads();
    if (o < 16){
        const float sc2 = 2.0f / (float)NN;
        float tr =  (os[ml][o][0] + os[ml][31-o][0]) * sc2;
        float ti = -((os[ml][o][1] + os[ml][31-o][1]) * sc2);
        const int mc4 = m / 216;
        const int mr  = m % 216;
        const int kk  = mr >> 2;
        const int qq  = mr & 3;
        unsigned pv = pk_bf16(tr, ti);
        *(unsigned*)(Abf + (size_t)b*27648 + ((size_t)kk*64 + mc4*16 + o)*8 + 2*qq) = pv;
    }
}

// ---------------- inverse NUFFT: MFMA, 12-wave blocks, coalesced A-loads ----------------
__global__ __launch_bounds__(768)
void inv_kernel(const float* __restrict__ pos, const short* __restrict__ Abf,
                float* __restrict__ y){
    const int tid = threadIdx.x;
    const int og  = tid >> 8;            // 0..2  (o-group)
    const int w4  = (tid >> 6) & 3;      // n-tile within block
    const int l   = tid & 63;
    const int col = l & 15;
    const int c4  = l >> 4;
    const int b   = blockIdx.y;
    const int n   = blockIdx.x*64 + w4*16 + col;

    __shared__ float red[2][4][16][17];

    const float px = pos[((size_t)b*NN + n)*3 + 0];
    const float py = pos[((size_t)b*NN + n)*3 + 1];
    const float pz = pos[((size_t)b*NN + n)*3 + 2];
    const float2 Ex = make_float2(hw_cos(px), hw_sin(px));   // exp(+i*2pi*px)
    const float2 Ey = make_float2(hw_cos(py), hw_sin(py));
    const float2 Ez = make_float2(hw_cos(pz), hw_sin(pz));

    const float2 yy2 = cmul(Ey, Ey);
    const float2 yy4 = cmul(yy2, yy2);
    const float2 yy8 = cmul(yy4, yy4);
    const float2 cj11 = conj2(cmul(cmul(yy8, yy2), Ey));   // Ey^-11
    const float2 x3  = cmul(cmul(Ex, Ex), Ex);
    const float2 x6  = cmul(x3, x3);
    float2 e = (c4==0) ? make_float2(1.f, 0.f)
             : (c4==1) ? x3
             : (c4==2) ? conj2(x6)
             :           conj2(x3);
    if (og >= 1) e = cmul(e, Ex);        // o-group start: kx += og
    if (og == 2) e = cmul(e, Ex);

    // coalesced fragment-major A: lane l reads 16B at base + l*16B, step 1KB per u2
    const short* Ab = Abf + (size_t)b*27648 + (size_t)og*18*512 + (size_t)l*8;
    f32x4 acc = {0.f, 0.f, 0.f, 0.f};

    union BU { unsigned u[4]; bf16x8 v; };

    // ky-ladder: segment advance S *= Ey (or Ey^-11 at the 5->-6 wrap), 5-deep Ez chains
    float2 S  = e;
    float2 ee = S;
    #pragma unroll
    for (int u2=0; u2<18; ++u2){
        BU bu;
        #pragma unroll
        for (int qq=0; qq<4; ++qq){
            const int g = 4*u2 + qq;              // 0..71 within o-group
            if (g > 0){
                if (g % 6) ee = cmul(ee, Ez);
                else { S = cmul(S, (g==36) ? cj11 : Ey); ee = S; }
            }
            bu.u[qq] = pk_bf16(ee.x, ee.y);
        }
        bf16x8 afr = *(const bf16x8*)(Ab + (size_t)u2*512);
        acc = __builtin_amdgcn_mfma_f32_16x16x32_bf16(afr, bu.v, acc, 0, 0, 0);
    }

    if (og >= 1){
        #pragma unroll
        for (int r=0; r<4; ++r) red[og-1][w4][c4*4 + r][col] = acc[r];
    }
    __syncthreads();
    if (og == 0){
        float* yb = y + (size_t)b*CC*NN + n;
        #pragma unroll
        for (int r=0; r<4; ++r){
            const int ch = c4*4 + r;
            float v = acc[r] + red[0][w4][ch][col] + red[1][w4][ch][col];
            __builtin_nontemporal_store(v, yb + (size_t)ch*NN);
            __builtin_nontemporal_store(v, yb + (size_t)(31-ch)*NN);
        }
    }
}

extern "C" void kernel_launch(void* const* d_in, const int* in_sizes, int n_in,
                              void* d_out, int out_size, void* d_ws, size_t ws_size,
                              hipStream_t stream){
    const float* x   = (const float*)d_in[0];
    const float* pos = (const float*)d_in[1];
    const float* w1  = (const float*)d_in[2];
    const float* w2  = (const float*)d_in[3];
    const float* w3  = (const float*)d_in[4];
    const float* w4  = (const float*)d_in[5];
    float* out = (float*)d_out;
    char* wsb = (char*)d_ws;

    // ws layout (bytes):
    float* wt    = (float*)(wsb);                // 4*216*1024*2*4 = 7,077,888
    short* Abf   = (short*)(wsb + 7520256);      // 2*27648*2     =   110,592
    float* part2 = (float*)(wsb + 7741440);      // 32*110592*4   = 14,155,776
    const bool use_part = (ws_size >= 21897216ull);

    if (use_part){
        fused_fwd_kernel<<<dim3(832), 256, 0, stream>>>(x, pos, w1, w2, w3, w4, wt, part2);
        mix_kernel<32><<<dim3(216,2), 128, 0, stream>>>(part2, wt, Abf);
    } else {
        wtrans_kernel<<<dim3(216,4), 256, 0, stream>>>(w1, w2, w3, w4, wt);
        (void)hipMemsetAsync(part2, 0, 442368, stream);
        fwd_atomic_kernel<<<dim3(64,9,2), 128, 0, stream>>>(x, pos, part2);
        mix_kernel<1><<<dim3(216,2), 128, 0, stream>>>(part2, wt, Abf);
    }

    inv_kernel<<<dim3(NN/64, BB), 768, 0, stream>>>(pos, Abf, out);
}